// Round 1
// baseline (32.573 us; speedup 1.0000x reference)
//
#include <hip/hip_runtime.h>

#define L 8192
#define ATT 1024
#define NPREV 8

__device__ inline float fast_tanh(float x) {
    // tanh(x) = 1 - 2/(exp(2x)+1); saturates correctly at +/-inf
    float e = __expf(2.0f * x);
    return 1.0f - 2.0f / (e + 1.0f);
}

// blocks 0..255: matvec dec_tiled[a] = dot(dec_z, mlp_dec_w[a,:]) + b[a], wave-per-output
// blocks 256..287: cov[l] = sum_p att_prev[p][l]; also copy old att rows to out
__global__ __launch_bounds__(256) void k_prep(
    const float* __restrict__ dec_z, const float* __restrict__ mlp_dec_w,
    const float* __restrict__ mlp_dec_b, const float* __restrict__ att_prev,
    float* __restrict__ dec_tiled, float* __restrict__ cov,
    float* __restrict__ out_att)
{
    int b = blockIdx.x;
    int t = threadIdx.x;
    if (b < 256) {
        int wave = t >> 6, lane = t & 63;
        int a = b * 4 + wave;
        const float4* wrow = (const float4*)(mlp_dec_w + a * ATT);
        const float4* dz   = (const float4*)dec_z;
        float s = 0.f;
        #pragma unroll
        for (int k = 0; k < 4; ++k) {
            int i = lane + 64 * k;
            float4 wv = wrow[i];
            float4 zv = dz[i];
            s += wv.x * zv.x + wv.y * zv.y + wv.z * zv.z + wv.w * zv.w;
        }
        #pragma unroll
        for (int off = 32; off; off >>= 1) s += __shfl_down(s, off, 64);
        if (lane == 0) dec_tiled[a] = s + mlp_dec_b[a];
    } else {
        int l = (b - 256) * 256 + t;
        float s = 0.f;
        #pragma unroll
        for (int p = 0; p < NPREV; ++p) {
            float v = att_prev[p * L + l];
            s += v;
            out_att[p * L + l] = v;
        }
        cov[l] = s;
    }
}

// wave-per-row score: e2[l] = 2*(sum_a tanh(cov*ww+wb+pre+dec)*gw + gb + mask[l])
__global__ __launch_bounds__(256) void k_score(
    const float* __restrict__ pre_enc, const float* __restrict__ cov,
    const float* __restrict__ wvec_w, const float* __restrict__ wvec_b,
    const float* __restrict__ dec_tiled, const float* __restrict__ gvec_w,
    const float* __restrict__ gvec_b, const float* __restrict__ mask,
    float* __restrict__ e2)
{
    int wave = threadIdx.x >> 6, lane = threadIdx.x & 63;
    int l = blockIdx.x * 4 + wave;
    float cv = cov[l];
    const float4* row = (const float4*)(pre_enc + (size_t)l * ATT);
    const float4* ww  = (const float4*)wvec_w;
    const float4* wb  = (const float4*)wvec_b;
    const float4* dt  = (const float4*)dec_tiled;
    const float4* gw  = (const float4*)gvec_w;
    float s = 0.f;
    #pragma unroll
    for (int k = 0; k < 4; ++k) {
        int i = lane + 64 * k;
        float4 pe = row[i];
        float4 w4 = ww[i], b4 = wb[i], d4 = dt[i], g4 = gw[i];
        s += fast_tanh(cv * w4.x + b4.x + pe.x + d4.x) * g4.x;
        s += fast_tanh(cv * w4.y + b4.y + pe.y + d4.y) * g4.y;
        s += fast_tanh(cv * w4.z + b4.z + pe.z + d4.z) * g4.z;
        s += fast_tanh(cv * w4.w + b4.w + pe.w + d4.w) * g4.w;
    }
    #pragma unroll
    for (int off = 32; off; off >>= 1) s += __shfl_down(s, off, 64);
    if (lane == 0) e2[l] = 2.0f * (s + gvec_b[0] + mask[l]);
}

// single-block softmax over 8192 scaled scores; writes w into out row 8
__global__ __launch_bounds__(1024) void k_softmax(
    const float* __restrict__ e2, float* __restrict__ w_out)
{
    __shared__ float red[16];
    __shared__ float smax, sinv;
    int t = threadIdx.x;
    float vals[8];
    float m = -1e30f;
    #pragma unroll
    for (int i = 0; i < 8; ++i) {
        vals[i] = e2[t + i * 1024];
        m = fmaxf(m, vals[i]);
    }
    #pragma unroll
    for (int off = 32; off; off >>= 1) m = fmaxf(m, __shfl_down(m, off, 64));
    if ((t & 63) == 0) red[t >> 6] = m;
    __syncthreads();
    if (t == 0) {
        float mm = red[0];
        for (int i = 1; i < 16; ++i) mm = fmaxf(mm, red[i]);
        smax = mm;
    }
    __syncthreads();
    float mx = smax;
    float s = 0.f;
    #pragma unroll
    for (int i = 0; i < 8; ++i) {
        vals[i] = __expf(vals[i] - mx);
        s += vals[i];
    }
    #pragma unroll
    for (int off = 32; off; off >>= 1) s += __shfl_down(s, off, 64);
    if ((t & 63) == 0) red[t >> 6] = s;
    __syncthreads();
    if (t == 0) {
        float ss = 0.f;
        for (int i = 0; i < 16; ++i) ss += red[i];
        sinv = 1.0f / ss;
    }
    __syncthreads();
    float inv = sinv;
    #pragma unroll
    for (int i = 0; i < 8; ++i) w_out[t + i * 1024] = vals[i] * inv;
}

// 64 blocks, each accumulates 128 rows of enc_h weighted by w -> partial[64][1024]
__global__ __launch_bounds__(256) void k_ctx_partial(
    const float* __restrict__ enc_h, const float* __restrict__ w,
    float* __restrict__ partial)
{
    int b = blockIdx.x;
    int t = threadIdx.x;
    float4 acc = {0.f, 0.f, 0.f, 0.f};
    const float4* enc = (const float4*)enc_h;
    for (int r = 0; r < 128; ++r) {
        int l = b * 128 + r;
        float wl = w[l];
        float4 v = enc[(size_t)l * 256 + t];
        acc.x += wl * v.x; acc.y += wl * v.y;
        acc.z += wl * v.z; acc.w += wl * v.w;
    }
    ((float4*)partial)[b * 256 + t] = acc;
}

// final 64-way reduce -> c[1024]
__global__ __launch_bounds__(256) void k_ctx_reduce(
    const float* __restrict__ partial, float* __restrict__ c)
{
    int j = blockIdx.x * 256 + threadIdx.x;
    float s = 0.f;
    for (int k = 0; k < 64; ++k) s += partial[k * 1024 + j];
    c[j] = s;
}

extern "C" void kernel_launch(void* const* d_in, const int* in_sizes, int n_in,
                              void* d_out, int out_size, void* d_ws, size_t ws_size,
                              hipStream_t stream) {
    const float* dec_z     = (const float*)d_in[0];
    const float* att_prev  = (const float*)d_in[1];
    const float* pre_enc   = (const float*)d_in[2];
    const float* enc_h     = (const float*)d_in[3];
    const float* mask      = (const float*)d_in[4];
    const float* wvec_w    = (const float*)d_in[5];
    const float* wvec_b    = (const float*)d_in[6];
    const float* mlp_dec_w = (const float*)d_in[7];
    const float* mlp_dec_b = (const float*)d_in[8];
    const float* gvec_w    = (const float*)d_in[9];
    const float* gvec_b    = (const float*)d_in[10];

    float* out     = (float*)d_out;
    float* out_c   = out;            // [1024]
    float* out_att = out + 1024;     // [9*8192]

    float* ws        = (float*)d_ws;
    float* dec_tiled = ws;                       // 1024
    float* cov       = ws + 1024;                // 8192
    float* e2        = ws + 1024 + 8192;         // 8192
    float* partial   = ws + 1024 + 8192 + 8192;  // 64*1024

    k_prep<<<288, 256, 0, stream>>>(dec_z, mlp_dec_w, mlp_dec_b, att_prev,
                                    dec_tiled, cov, out_att);
    k_score<<<2048, 256, 0, stream>>>(pre_enc, cov, wvec_w, wvec_b, dec_tiled,
                                      gvec_w, gvec_b, mask, e2);
    k_softmax<<<1, 1024, 0, stream>>>(e2, out_att + 8 * L);
    k_ctx_partial<<<64, 256, 0, stream>>>(enc_h, out_att + 8 * L, partial);
    k_ctx_reduce<<<4, 256, 0, stream>>>(partial, out_c);
}